// Round 1
// baseline (249.364 us; speedup 1.0000x reference)
//
#include <hip/hip_runtime.h>
#include <stdint.h>

// Problem constants
#define BB 4
#define SS 2048
#define PP 8
#define FIN 1024
#define FOUT 1024
#define MROWS (BB*SS)          // 8192 rows per group
#define ROWSTRIDE (PP*FIN)     // 8192 floats between consecutive (b,s) rows
#define OROWSTRIDE (PP*FOUT)

// Tile config
#define BM 128
#define BN 128
#define BK 64
#define NKT (FIN/BK)           // 16 K-steps

typedef float fx4 __attribute__((ext_vector_type(4)));
typedef short sv8 __attribute__((ext_vector_type(8)));   // 8 bf16 as shorts (MFMA frag)

union BCvt { sv8 s; __bf16 b[8]; };

__device__ __forceinline__ unsigned short bfbits(float f) {
    union { __bf16 b; unsigned short u; } c; c.b = (__bf16)f; return c.u;
}

__device__ __forceinline__ sv8 cvt8(fx4 lo, fx4 hi) {
    BCvt u;
#pragma unroll
    for (int i = 0; i < 4; ++i) { u.b[i] = (__bf16)lo[i]; u.b[i + 4] = (__bf16)hi[i]; }
    return u.s;
}

// ---------------------------------------------------------------------------
// Prepass: W [P][K][N] fp32  ->  Wt [P][N][K] bf16   (16.8 MB into d_ws)
// ---------------------------------------------------------------------------
__global__ __launch_bounds__(256) void wtrans(const float* __restrict__ w,
                                              unsigned short* __restrict__ wt) {
    __shared__ unsigned short L[64 * 66];   // [k][n], pad 66 to break bank patterns
    const int bid = blockIdx.x;             // 8 * 16 * 16 = 2048 blocks
    const int p  = bid >> 8;
    const int rem = bid & 255;
    const int k0 = (rem >> 4) * 64;
    const int n0 = (rem & 15) * 64;
    const int t = threadIdx.x;

    const int nf = t & 15, kl0 = t >> 4;
#pragma unroll
    for (int rr = 0; rr < 4; ++rr) {
        const int kl = kl0 + rr * 16;
        const float* s = w + p * (FIN*FOUT) + (k0 + kl) * FOUT + n0 + nf * 4;
        fx4 v = *(const fx4*)s;
        unsigned short* d = &L[kl * 66 + nf * 4];
        d[0] = bfbits(v[0]); d[1] = bfbits(v[1]); d[2] = bfbits(v[2]); d[3] = bfbits(v[3]);
    }
    __syncthreads();
    const int kg = t & 7, nl0 = t >> 3;
#pragma unroll
    for (int rr = 0; rr < 2; ++rr) {
        const int n = nl0 + rr * 32;
        union { sv8 s; unsigned short us[8]; } u;
#pragma unroll
        for (int e = 0; e < 8; ++e) u.us[e] = L[(kg * 8 + e) * 66 + n];
        *(sv8*)(wt + (p * 1024 + n0 + n) * 1024 + k0 + kg * 8) = u.s;
    }
}

// ---------------------------------------------------------------------------
// Grouped GEMM: out[m, p, n] = sum_k x[m, p, k] * W[p, k, n] + bias[p, n]
// TIER 1: B-operand from pre-transposed bf16 Wt in d_ws
// TIER 0: B-operand staged from fp32 W via coalesced k-strided scalar loads
// ---------------------------------------------------------------------------

// A staging: rr in [0,4): kg = tid&7 (8 bf16 k-chunk), m = (tid>>3) + rr*32
#define LOADA(kt, rset) do {                                                          \
    _Pragma("unroll")                                                                 \
    for (int rr = 0; rr < 4; ++rr) {                                                  \
        const float* s_ = x + (m0 + a_m + rr * 32) * ROWSTRIDE + p * FIN              \
                            + (kt) * BK + a_kg * 8;                                   \
        rset[rr][0] = *(const fx4*)s_;                                                \
        rset[rr][1] = *(const fx4*)(s_ + 4);                                          \
    }                                                                                 \
} while (0)

#define STOREA(rset, buf) do {                                                        \
    _Pragma("unroll")                                                                 \
    for (int rr = 0; rr < 4; ++rr) {                                                  \
        const int m_ = a_m + rr * 32;                                                 \
        const int byte_ = m_ * 128 + ((a_kg * 16) ^ ((m_ & 7) << 4));                 \
        *(sv8*)(ldsA[buf] + byte_) = cvt8(rset[rr][0], rset[rr][1]);                  \
    }                                                                                 \
} while (0)

#define LOADB1(kt, rset) do {                                                         \
    _Pragma("unroll")                                                                 \
    for (int rr = 0; rr < 4; ++rr) {                                                  \
        rset[rr] = *(const sv8*)(wt + (p * 1024 + n0 + b_n + rr * 32) * 1024          \
                                    + (kt) * BK + b_kg * 8);                          \
    }                                                                                 \
} while (0)

#define STOREB1(rset, buf) do {                                                       \
    _Pragma("unroll")                                                                 \
    for (int rr = 0; rr < 4; ++rr) {                                                  \
        const int n_ = b_n + rr * 32;                                                 \
        const int byte_ = n_ * 128 + ((b_kg * 16) ^ ((n_ & 7) << 4));                 \
        *(sv8*)(ldsB[buf] + byte_) = rset[rr];                                        \
    }                                                                                 \
} while (0)

#define LOADB0(kt, rset) do {                                                         \
    _Pragma("unroll")                                                                 \
    for (int rr = 0; rr < 4; ++rr) {                                                  \
        const int kg_ = b0_kg + rr * 2;                                               \
        _Pragma("unroll")                                                             \
        for (int e = 0; e < 8; ++e)                                                   \
            rset[rr][e] = w[p * (FIN*FOUT) + ((kt) * BK + kg_ * 8 + e) * FOUT         \
                            + n0 + b0_n];                                             \
    }                                                                                 \
} while (0)

#define STOREB0(rset, buf) do {                                                       \
    _Pragma("unroll")                                                                 \
    for (int rr = 0; rr < 4; ++rr) {                                                  \
        const int kg_ = b0_kg + rr * 2;                                               \
        const int byte_ = b0_n * 128 + ((kg_ * 16) ^ ((b0_n & 7) << 4));              \
        BCvt u_;                                                                      \
        _Pragma("unroll")                                                             \
        for (int e = 0; e < 8; ++e) u_.b[e] = (__bf16)rset[rr][e];                    \
        *(sv8*)(ldsB[buf] + byte_) = u_.s;                                            \
    }                                                                                 \
} while (0)

#define MFMA_PHASE(buf) do {                                                          \
    const char* Ab_ = ldsA[buf]; const char* Bb_ = ldsB[buf];                         \
    _Pragma("unroll")                                                                 \
    for (int ks = 0; ks < 2; ++ks) {                                                  \
        sv8 af_[4], bfr_[4];                                                          \
        _Pragma("unroll")                                                             \
        for (int f = 0; f < 4; ++f) {                                                 \
            const int row_ = wm * 64 + f * 16 + (lane & 15);                          \
            af_[f] = *(const sv8*)(Ab_ + row_ * 128 +                                 \
                       ((ks * 64 + (lane >> 4) * 16) ^ ((row_ & 7) << 4)));           \
        }                                                                             \
        _Pragma("unroll")                                                             \
        for (int f = 0; f < 4; ++f) {                                                 \
            const int row_ = wn * 64 + f * 16 + (lane & 15);                          \
            bfr_[f] = *(const sv8*)(Bb_ + row_ * 128 +                                \
                       ((ks * 64 + (lane >> 4) * 16) ^ ((row_ & 7) << 4)));           \
        }                                                                             \
        _Pragma("unroll")                                                             \
        for (int i = 0; i < 4; ++i)                                                   \
            _Pragma("unroll")                                                         \
            for (int j = 0; j < 4; ++j)                                               \
                acc[i][j] = __builtin_amdgcn_mfma_f32_16x16x32_bf16(                  \
                                af_[i], bfr_[j], acc[i][j], 0, 0, 0);                 \
    }                                                                                 \
} while (0)

template <int TIER>
__global__ __launch_bounds__(256, 2)
void pd_gemm(const float* __restrict__ x, const float* __restrict__ w,
             const unsigned short* __restrict__ wt, const float* __restrict__ bias,
             float* __restrict__ out) {
    __shared__ __align__(16) char ldsA[2][BM * BK * 2];   // 2 x 16 KB, swizzled bf16
    __shared__ __align__(16) char ldsB[2][BN * BK * 2];   // 2 x 16 KB

    const int tid = threadIdx.x;
    const int lane = tid & 63;
    const int wv = tid >> 6;           // 4 waves: 2x2 over the 128x128 tile
    const int wm = wv >> 1, wn = wv & 1;

    // XCD swizzle: 4096 blocks, 8 XCDs, 512 blocks/XCD == exactly one group.
    const int bid = blockIdx.x;
    const int swz = (bid & 7) * 512 + (bid >> 3);
    const int p   = swz >> 9;          // group == XCD -> W_p lives in that XCD's L2
    const int wrk = swz & 511;
    const int n0  = (wrk & 7) * BN;    // n fastest: 8 consecutive blocks share A-panel
    const int m0  = (wrk >> 3) * BM;

    const int a_kg = tid & 7, a_m = tid >> 3;
    const int b_kg = tid & 7, b_n = tid >> 3;
    const int b0_n = (tid & 63) + ((wv & 1) << 6);
    const int b0_kg = wv >> 1;

    fx4 acc[4][4];
#pragma unroll
    for (int i = 0; i < 4; ++i)
#pragma unroll
        for (int j = 0; j < 4; ++j) acc[i][j] = (fx4)0.0f;

    if constexpr (TIER == 1) {
        fx4 rA0[4][2], rA1[4][2];
        sv8 rB0v[4], rB1v[4];
        LOADA(0, rA0); LOADB1(0, rB0v);
        for (int kk = 0; kk < NKT / 2; ++kk) {
            const int kt = kk * 2;
            LOADA(kt + 1, rA1); LOADB1(kt + 1, rB1v);
            STOREA(rA0, 0); STOREB1(rB0v, 0);
            __syncthreads();
            MFMA_PHASE(0);
            if (kt + 2 < NKT) { LOADA(kt + 2, rA0); LOADB1(kt + 2, rB0v); }
            STOREA(rA1, 1); STOREB1(rB1v, 1);
            __syncthreads();
            MFMA_PHASE(1);
        }
    } else {
        fx4 rA0[4][2], rA1[4][2];
        float rB0f[4][8], rB1f[4][8];
        LOADA(0, rA0); LOADB0(0, rB0f);
        for (int kk = 0; kk < NKT / 2; ++kk) {
            const int kt = kk * 2;
            LOADA(kt + 1, rA1); LOADB0(kt + 1, rB1f);
            STOREA(rA0, 0); STOREB0(rB0f, 0);
            __syncthreads();
            MFMA_PHASE(0);
            if (kt + 2 < NKT) { LOADA(kt + 2, rA0); LOADB0(kt + 2, rB0f); }
            STOREA(rA1, 1); STOREB0(rB1f, 1);
            __syncthreads();
            MFMA_PHASE(1);
        }
    }

    // Epilogue: C/D layout col = lane&15, row = (lane>>4)*4 + j (m89/m91-verified)
    const float* bs = bias + p * FOUT;
#pragma unroll
    for (int fn = 0; fn < 4; ++fn) {
        const int col = n0 + wn * 64 + fn * 16 + (lane & 15);
        const float bv = bs[col];
#pragma unroll
        for (int fm = 0; fm < 4; ++fm) {
            const int row = m0 + wm * 64 + fm * 16 + (lane >> 4) * 4;
            float* o = out + row * OROWSTRIDE + p * FOUT + col;
#pragma unroll
            for (int j = 0; j < 4; ++j)
                o[j * OROWSTRIDE] = acc[fm][fn][j] + bv;
        }
    }
}

extern "C" void kernel_launch(void* const* d_in, const int* in_sizes, int n_in,
                              void* d_out, int out_size, void* d_ws, size_t ws_size,
                              hipStream_t stream) {
    const float* x    = (const float*)d_in[0];
    const float* w    = (const float*)d_in[1];
    const float* bias = (const float*)d_in[2];
    float* out = (float*)d_out;

    const size_t WT_BYTES = (size_t)PP * FIN * FOUT * sizeof(unsigned short);  // 16.8 MB
    const int nblk = PP * (MROWS / BM) * (FOUT / BN);   // 8*64*8 = 4096

    if (ws_size >= WT_BYTES) {
        unsigned short* wt = (unsigned short*)d_ws;
        wtrans<<<dim3(2048), dim3(256), 0, stream>>>(w, wt);
        pd_gemm<1><<<dim3(nblk), dim3(256), 0, stream>>>(x, w, wt, bias, out);
    } else {
        pd_gemm<0><<<dim3(nblk), dim3(256), 0, stream>>>(x, w, nullptr, bias, out);
    }
}